// Round 1
// baseline (164.413 us; speedup 1.0000x reference)
//
#include <hip/hip_runtime.h>

// RgbNet: hash-grid encode (5 samples/ray, 6 levels, trilinear) + MLP 120->64->64->64->3.
// Design: block = 256 threads = 4 waves, handles 64 rays.
//   Phase 0: 64 rays x 30 (sample,level) pairs; thread = (pair,ray); 8 float4 gathers each,
//            trilinear-weighted sum -> LDS feat[k][ray] (k-major, stride 64, conflict-free).
//   Phase 1-3: lane = ray, wave w owns neurons j in [16w,16w+16); weights via wave-uniform
//              scalar loads (readfirstlane-forced); activations exchanged through LDS.
//   Phase 4: waves 0..2 compute the 3 outputs.

#define NSAMP 300
#define HSIZE (1u << 19)

__global__ __launch_bounds__(256, 1) void rgbnet_fused(
    const float4* __restrict__ x,       // [N] rows: sx,sy,ex,ey
    const int*    __restrict__ idxf,    // [N]
    const float4* __restrict__ emb,     // [6 * 2^19] float4 entries
    const float* __restrict__ W1, const float* __restrict__ b1,
    const float* __restrict__ W2, const float* __restrict__ b2,
    const float* __restrict__ W3, const float* __restrict__ b3,
    const float* __restrict__ W4, const float* __restrict__ b4,
    float* __restrict__ out, int N)
{
    __shared__ float sFeat[120 * 64];   // 30720 B
    __shared__ float sHa[64 * 64];      // 16384 B
    __shared__ float sHb[64 * 64];      // 16384 B  (total 63488 <= 64KB)

    const int tid  = threadIdx.x;
    const int r    = tid & 63;                 // local ray
    const int wsub = tid >> 6;                 // wave id 0..3 (divergent to compiler)
    const int ray  = blockIdx.x * 64 + r;

    const float4 xr = x[ray];
    const int    i0 = idxf[ray];
    const float sx = xr.x, sy = xr.y, ex = xr.z, ey = xr.w;

    // ---------------- Phase 0: grid encoding ----------------
    for (int iter = 0; iter < 8; ++iter) {
        const int p = iter * 4 + wsub;         // pair id, wave-uniform at runtime
        if (p < 30) {
            const int d = p / 6;               // gather offset index 0..4  (d-2 in ref)
            const int l = p - d * 6;           // level 0..5
            int s = i0 + d - 2;
            s = max(0, min(s, NSAMP - 1));
            const float t   = (float)s * (1.0f / 299.0f);
            const float omt = 1.0f - t;
            const int   R   = 4 << l;
            const float fR  = (float)R;
            const float px = (sx * omt + ex * t) * fR;
            const float py = (sy * omt + ey * t) * fR;
            const float pz = t * fR;
            const float fx0 = floorf(px), fy0 = floorf(py), fz0 = floorf(pz);
            const float wx = px - fx0, wy = py - fy0, wz = pz - fz0;
            const int ix = (int)fx0, iy = (int)fy0, iz = (int)fz0;
            const int Rp1 = R + 1;
            const float4* __restrict__ ebase = emb + (size_t)l * HSIZE;

            float ax = 0.f, ay = 0.f, az = 0.f, aw = 0.f;
            #pragma unroll
            for (int c = 0; c < 8; ++c) {
                const int ox = (c >> 2) & 1, oy = (c >> 1) & 1, oz = c & 1;
                int cx = min(ix + ox, R); cx = max(cx, 0);
                int cy = min(iy + oy, R); cy = max(cy, 0);
                int cz = min(iz + oz, R); cz = max(cz, 0);
                unsigned idx;
                if (l < 5) {
                    idx = (unsigned)(cx + cy * Rp1 + cz * Rp1 * Rp1);   // dense level
                } else {
                    idx = ((unsigned)cx * 1u
                         ^ (unsigned)cy * 2654435761u
                         ^ (unsigned)cz * 805459861u) & (HSIZE - 1u);   // hashed level
                }
                const float4 e = ebase[idx];
                const float cw = (ox ? wx : 1.f - wx)
                               * (oy ? wy : 1.f - wy)
                               * (oz ? wz : 1.f - wz);
                ax = fmaf(cw, e.x, ax);
                ay = fmaf(cw, e.y, ay);
                az = fmaf(cw, e.z, az);
                aw = fmaf(cw, e.w, aw);
            }
            const int k0 = p * 4;              // = d*24 + l*4, matches ref concat order
            sFeat[(k0 + 0) * 64 + r] = ax;
            sFeat[(k0 + 1) * 64 + r] = ay;
            sFeat[(k0 + 2) * 64 + r] = az;
            sFeat[(k0 + 3) * 64 + r] = aw;
        }
    }
    __syncthreads();

    // Force wave id into an SGPR so all weight addresses are provably uniform -> s_load.
    const int wu = __builtin_amdgcn_readfirstlane(wsub);
    const int j0 = wu * 16;

    float hh[16];

    // ---------------- Layer 1: 120 -> 64 ----------------
    #pragma unroll
    for (int jj = 0; jj < 16; ++jj) hh[jj] = b1[j0 + jj];
    #pragma unroll 8
    for (int k = 0; k < 120; ++k) {
        const float f = sFeat[k * 64 + r];
        #pragma unroll
        for (int jj = 0; jj < 16; ++jj)
            hh[jj] = fmaf(f, W1[(j0 + jj) * 120 + k], hh[jj]);
    }
    #pragma unroll
    for (int jj = 0; jj < 16; ++jj)
        sHa[(j0 + jj) * 64 + r] = fmaxf(hh[jj], 0.f);
    __syncthreads();

    // ---------------- Layer 2: 64 -> 64 ----------------
    #pragma unroll
    for (int jj = 0; jj < 16; ++jj) hh[jj] = b2[j0 + jj];
    #pragma unroll 8
    for (int k = 0; k < 64; ++k) {
        const float f = sHa[k * 64 + r];
        #pragma unroll
        for (int jj = 0; jj < 16; ++jj)
            hh[jj] = fmaf(f, W2[(j0 + jj) * 64 + k], hh[jj]);
    }
    #pragma unroll
    for (int jj = 0; jj < 16; ++jj)
        sHb[(j0 + jj) * 64 + r] = fmaxf(hh[jj], 0.f);
    __syncthreads();

    // ---------------- Layer 3: 64 -> 64 ----------------
    #pragma unroll
    for (int jj = 0; jj < 16; ++jj) hh[jj] = b3[j0 + jj];
    #pragma unroll 8
    for (int k = 0; k < 64; ++k) {
        const float f = sHb[k * 64 + r];
        #pragma unroll
        for (int jj = 0; jj < 16; ++jj)
            hh[jj] = fmaf(f, W3[(j0 + jj) * 64 + k], hh[jj]);
    }
    #pragma unroll
    for (int jj = 0; jj < 16; ++jj)
        sHa[(j0 + jj) * 64 + r] = fmaxf(hh[jj], 0.f);
    __syncthreads();

    // ---------------- Output: 64 -> 3 ----------------
    if (wu < 3) {
        float acc = b4[wu];
        #pragma unroll 8
        for (int k = 0; k < 64; ++k)
            acc = fmaf(sHa[k * 64 + r], W4[wu * 64 + k], acc);
        out[(size_t)ray * 3 + wu] = acc;
    }
}

extern "C" void kernel_launch(void* const* d_in, const int* in_sizes, int n_in,
                              void* d_out, int out_size, void* d_ws, size_t ws_size,
                              hipStream_t stream) {
    const float4* x    = (const float4*)d_in[0];
    const int*    idxf = (const int*)   d_in[1];
    const float4* emb  = (const float4*)d_in[2];
    const float*  W1   = (const float*) d_in[3];
    const float*  b1   = (const float*) d_in[4];
    const float*  W2   = (const float*) d_in[5];
    const float*  b2   = (const float*) d_in[6];
    const float*  W3   = (const float*) d_in[7];
    const float*  b3   = (const float*) d_in[8];
    const float*  W4   = (const float*) d_in[9];
    const float*  b4   = (const float*) d_in[10];
    float* out = (float*)d_out;

    const int N = in_sizes[0] / 4;              // 16384 rays (x is [N,4])
    const int blocks = (N + 63) / 64;           // 64 rays per block, N % 64 == 0
    hipLaunchKernelGGL(rgbnet_fused, dim3(blocks), dim3(256), 0, stream,
                       x, idxf, emb, W1, b1, W2, b2, W3, b3, W4, b4, out, N);
}

// Round 2
// 128.288 us; speedup vs baseline: 1.2816x; 1.2816x over previous
//
#include <hip/hip_runtime.h>

// RgbNet: hash-grid encode (5 samples/ray, 6 levels, trilinear) + MLP 120->64->64->64->3.
// Design: block = 1024 threads = 16 waves, handles 64 rays (grid = 256 blocks, 1/CU).
//   Occupancy is grid-pinned at 1 block/CU, so waves/block is the only occupancy lever:
//   16 waves/block -> 16 waves/CU (~50%) vs 4 (~11%) in R0.
//   Phase 0: 30 (sample,level) pairs striped over waves (p = wsub, wsub+16); lane = ray;
//            8 float4 gathers each, trilinear sum -> LDS feat[k][ray] (stride 64, conflict-free).
//   Phase 1-3: lane = ray, wave w owns neurons [4w,4w+4); weight addresses are wave-uniform
//              (readfirstlane-forced) -> scalar s_load path; activations via LDS broadcast.
//   Phase 4: waves 0..2 compute the 3 output channels.

#define NSAMP 300
#define HSIZE (1u << 19)

__global__ __launch_bounds__(1024, 1) void rgbnet_fused(
    const float4* __restrict__ x,       // [N] rows: sx,sy,ex,ey
    const int*    __restrict__ idxf,    // [N]
    const float4* __restrict__ emb,     // [6 * 2^19] float4 entries
    const float* __restrict__ W1, const float* __restrict__ b1,
    const float* __restrict__ W2, const float* __restrict__ b2,
    const float* __restrict__ W3, const float* __restrict__ b3,
    const float* __restrict__ W4, const float* __restrict__ b4,
    float* __restrict__ out, int N)
{
    __shared__ float sFeat[120 * 64];   // 30720 B
    __shared__ float sHa[64 * 64];      // 16384 B
    __shared__ float sHb[64 * 64];      // 16384 B  (total 63488 <= 64KB)

    const int tid  = threadIdx.x;
    const int r    = tid & 63;                 // local ray (= lane)
    const int wsub = tid >> 6;                 // wave id 0..15
    const int ray  = blockIdx.x * 64 + r;

    // ---------------- Phase 0: grid encoding ----------------
    {
        const float4 xr = x[ray];
        const int    i0 = idxf[ray];
        const float sx = xr.x, sy = xr.y, ex = xr.z, ey = xr.w;

        for (int p = wsub; p < 30; p += 16) {  // wave-uniform pair id
            const int d = p / 6;               // gather offset index 0..4  (d-2 in ref)
            const int l = p - d * 6;           // level 0..5
            int s = i0 + d - 2;
            s = max(0, min(s, NSAMP - 1));
            const float t   = (float)s * (1.0f / 299.0f);
            const float omt = 1.0f - t;
            const int   R   = 4 << l;
            const float fR  = (float)R;
            const float px = (sx * omt + ex * t) * fR;
            const float py = (sy * omt + ey * t) * fR;
            const float pz = t * fR;
            const float fx0 = floorf(px), fy0 = floorf(py), fz0 = floorf(pz);
            const float wx = px - fx0, wy = py - fy0, wz = pz - fz0;
            const int ix = (int)fx0, iy = (int)fy0, iz = (int)fz0;
            const int Rp1 = R + 1;
            const float4* __restrict__ ebase = emb + (size_t)l * HSIZE;

            float ax = 0.f, ay = 0.f, az = 0.f, aw = 0.f;
            #pragma unroll
            for (int c = 0; c < 8; ++c) {
                const int ox = (c >> 2) & 1, oy = (c >> 1) & 1, oz = c & 1;
                int cx = min(ix + ox, R); cx = max(cx, 0);
                int cy = min(iy + oy, R); cy = max(cy, 0);
                int cz = min(iz + oz, R); cz = max(cz, 0);
                unsigned idx;
                if (l < 5) {
                    idx = (unsigned)(cx + cy * Rp1 + cz * Rp1 * Rp1);   // dense level
                } else {
                    idx = ((unsigned)cx * 1u
                         ^ (unsigned)cy * 2654435761u
                         ^ (unsigned)cz * 805459861u) & (HSIZE - 1u);   // hashed level
                }
                const float4 e = ebase[idx];
                const float cw = (ox ? wx : 1.f - wx)
                               * (oy ? wy : 1.f - wy)
                               * (oz ? wz : 1.f - wz);
                ax = fmaf(cw, e.x, ax);
                ay = fmaf(cw, e.y, ay);
                az = fmaf(cw, e.z, az);
                aw = fmaf(cw, e.w, aw);
            }
            const int k0 = p * 4;              // = d*24 + l*4, matches ref concat order
            sFeat[(k0 + 0) * 64 + r] = ax;
            sFeat[(k0 + 1) * 64 + r] = ay;
            sFeat[(k0 + 2) * 64 + r] = az;
            sFeat[(k0 + 3) * 64 + r] = aw;
        }
    }
    __syncthreads();

    // Force wave id into an SGPR so all weight addresses are provably uniform -> s_load.
    const int wu = __builtin_amdgcn_readfirstlane(wsub);
    const int j0 = wu * 4;                     // wave owns neurons j0..j0+3

    float hh[4];

    // ---------------- Layer 1: 120 -> 64 ----------------
    #pragma unroll
    for (int jj = 0; jj < 4; ++jj) hh[jj] = b1[j0 + jj];
    #pragma unroll 8
    for (int k = 0; k < 120; ++k) {
        const float f = sFeat[k * 64 + r];
        #pragma unroll
        for (int jj = 0; jj < 4; ++jj)
            hh[jj] = fmaf(f, W1[(j0 + jj) * 120 + k], hh[jj]);
    }
    #pragma unroll
    for (int jj = 0; jj < 4; ++jj)
        sHa[(j0 + jj) * 64 + r] = fmaxf(hh[jj], 0.f);
    __syncthreads();

    // ---------------- Layer 2: 64 -> 64 ----------------
    #pragma unroll
    for (int jj = 0; jj < 4; ++jj) hh[jj] = b2[j0 + jj];
    #pragma unroll 8
    for (int k = 0; k < 64; ++k) {
        const float f = sHa[k * 64 + r];
        #pragma unroll
        for (int jj = 0; jj < 4; ++jj)
            hh[jj] = fmaf(f, W2[(j0 + jj) * 64 + k], hh[jj]);
    }
    #pragma unroll
    for (int jj = 0; jj < 4; ++jj)
        sHb[(j0 + jj) * 64 + r] = fmaxf(hh[jj], 0.f);
    __syncthreads();

    // ---------------- Layer 3: 64 -> 64 ----------------
    #pragma unroll
    for (int jj = 0; jj < 4; ++jj) hh[jj] = b3[j0 + jj];
    #pragma unroll 8
    for (int k = 0; k < 64; ++k) {
        const float f = sHb[k * 64 + r];
        #pragma unroll
        for (int jj = 0; jj < 4; ++jj)
            hh[jj] = fmaf(f, W3[(j0 + jj) * 64 + k], hh[jj]);
    }
    #pragma unroll
    for (int jj = 0; jj < 4; ++jj)
        sHa[(j0 + jj) * 64 + r] = fmaxf(hh[jj], 0.f);
    __syncthreads();

    // ---------------- Output: 64 -> 3 ----------------
    if (wu < 3) {
        float acc = b4[wu];
        #pragma unroll 8
        for (int k = 0; k < 64; ++k)
            acc = fmaf(sHa[k * 64 + r], W4[wu * 64 + k], acc);
        out[(size_t)ray * 3 + wu] = acc;
    }
}

extern "C" void kernel_launch(void* const* d_in, const int* in_sizes, int n_in,
                              void* d_out, int out_size, void* d_ws, size_t ws_size,
                              hipStream_t stream) {
    const float4* x    = (const float4*)d_in[0];
    const int*    idxf = (const int*)   d_in[1];
    const float4* emb  = (const float4*)d_in[2];
    const float*  W1   = (const float*) d_in[3];
    const float*  b1   = (const float*) d_in[4];
    const float*  W2   = (const float*) d_in[5];
    const float*  b2   = (const float*) d_in[6];
    const float*  W3   = (const float*) d_in[7];
    const float*  b3   = (const float*) d_in[8];
    const float*  W4   = (const float*) d_in[9];
    const float*  b4   = (const float*) d_in[10];
    float* out = (float*)d_out;

    const int N = in_sizes[0] / 4;              // 16384 rays (x is [N,4])
    const int blocks = (N + 63) / 64;           // 64 rays per block
    hipLaunchKernelGGL(rgbnet_fused, dim3(blocks), dim3(1024), 0, stream,
                       x, idxf, emb, W1, b1, W2, b2, W3, b3, W4, b4, out, N);
}